// Round 11
// baseline (303.273 us; speedup 1.0000x reference)
//
#include <hip/hip_runtime.h>

typedef __attribute__((ext_vector_type(4))) int int4v;

constexpr int Mdim = 32768;   // 8*4096
constexpr int Kdim = 1024;
constexpr int Ndim = 1024;
constexpr float FEPS = 1e-8f;

// ---------------- ws layout (bytes) ----------------
// 0      : float scalars[8]  {gamma_w, gamma_b, scale, sg, qs, inv_scale}
// 1024   : float partials[256]   (|W| partial sums)
// 4096   : unsigned pmax[2048]   (per-block |x| max bits)
// 16384  : float bq[1024]
// 32768  : int8 wq (1 MB)  -- TILED: tile t=(nb*16+kt) is 1KB; byte l*16 of tile t
//                             holds W[nb*16 + (l&15)][kt*64 + (l>>4)*16 .. +15]
constexpr size_t WQ_OFF = 32768;
constexpr size_t WS_NEED = WQ_OFF + (size_t)Ndim * Kdim;

// ---------------- pass 1 (merged): |x| absmax partials + |W| sum partials ----
__global__ void k_pre(const uint4* __restrict__ xv, const float4* __restrict__ wv,
                      unsigned* __restrict__ pmax, float* __restrict__ partials) {
  const int tid = threadIdx.x;
  if (blockIdx.x < 2048) {
    int i0 = blockIdx.x * 256 + tid;
    const int stride = 2048 * 256;
    const int n4 = Mdim * Kdim / 4;
    unsigned m = 0u;
    for (int i = i0; i < n4; i += stride) {
      uint4 v = xv[i];
      m = max(m, v.x & 0x7fffffffu);
      m = max(m, v.y & 0x7fffffffu);
      m = max(m, v.z & 0x7fffffffu);
      m = max(m, v.w & 0x7fffffffu);
    }
    #pragma unroll
    for (int off = 32; off > 0; off >>= 1)
      m = max(m, (unsigned)__shfl_down((int)m, off, 64));
    __shared__ unsigned red[4];
    if ((tid & 63) == 0) red[tid >> 6] = m;
    __syncthreads();
    if (tid == 0)
      pmax[blockIdx.x] = max(max(red[0], red[1]), max(red[2], red[3]));
  } else {
    int wb = blockIdx.x - 2048;
    float s = 0.f;
    const int stride = 256 * 256;
    const int n4 = Ndim * Kdim / 4;
    for (int i = wb * 256 + tid; i < n4; i += stride) {
      float4 v = wv[i];
      s += fabsf(v.x) + fabsf(v.y) + fabsf(v.z) + fabsf(v.w);
    }
    __shared__ float red[256];
    red[tid] = s;
    __syncthreads();
    for (int h = 128; h > 0; h >>= 1) {
      if (tid < h) red[tid] += red[tid + h];
      __syncthreads();
    }
    if (tid == 0) partials[wb] = red[0];
  }
}

// ---------------- pass 2: scalars + bias quant + W quant (256 blocks) --------
__global__ void k_finalize2(const float* __restrict__ bias, const float* __restrict__ w,
                            const float* __restrict__ partials, const unsigned* __restrict__ pmax,
                            float* __restrict__ scalars, float* __restrict__ bq,
                            unsigned char* __restrict__ wq) {
  __shared__ float red[256];
  const int t = threadIdx.x;
  const int b = blockIdx.x;

  red[t] = partials[t];
  __syncthreads();
  for (int h = 128; h > 0; h >>= 1) {
    if (t < h) red[t] += red[t + h];
    __syncthreads();
  }
  const float gw = red[0] / (1024.0f * 1024.0f);
  __syncthreads();
  const float inv_g = gw + FEPS;

  {
    const int tile = b * 4 + (t >> 6);   // 0..1023
    const int nb = tile >> 4;
    const int kt = tile & 15;
    const int l = t & 63;
    const float4* src = (const float4*)(w + (size_t)(nb * 16 + (l >> 2)) * Kdim + kt * 64 + (l & 3) * 16);
    unsigned o[4];
    #pragma unroll
    for (int v = 0; v < 4; ++v) {
      float4 f = src[v];
      int a  = (int)rintf(fminf(fmaxf(f.x / inv_g, -1.f), 1.f));
      int bb = (int)rintf(fminf(fmaxf(f.y / inv_g, -1.f), 1.f));
      int cc = (int)rintf(fminf(fmaxf(f.z / inv_g, -1.f), 1.f));
      int dd = (int)rintf(fminf(fmaxf(f.w / inv_g, -1.f), 1.f));
      o[v] = (unsigned)(a & 0xff) | ((unsigned)(bb & 0xff) << 8) |
             ((unsigned)(cc & 0xff) << 16) | ((unsigned)(dd & 0xff) << 24);
    }
    uint4 pk; pk.x = o[0]; pk.y = o[1]; pk.z = o[2]; pk.w = o[3];
    const int lp = (l >> 2) | ((l & 3) << 4);   // fragment lane
    *(uint4*)(wq + (size_t)tile * 1024 + lp * 16) = pk;
  }

  if (b != 0) return;

  __shared__ unsigned redu[256];
  __shared__ float sh_gb;
  unsigned m = 0u;
  #pragma unroll
  for (int i = 0; i < 8; ++i) m = max(m, pmax[t + 256 * i]);
  redu[t] = m;
  float s = fabsf(bias[t]) + fabsf(bias[t + 256]) + fabsf(bias[t + 512]) + fabsf(bias[t + 768]);
  red[t] = s;
  __syncthreads();
  for (int h = 128; h > 0; h >>= 1) {
    if (t < h) {
      red[t] += red[t + h];
      redu[t] = max(redu[t], redu[t + h]);
    }
    __syncthreads();
  }
  if (t == 0) {
    float gb = red[0] / 1024.0f;
    float maxval = __uint_as_float(redu[0]);
    float v = maxval / 127.0f + FEPS;
    int e = (int)((__float_as_uint(v) >> 23) & 0xff) - 127;
    float scale = ldexpf(1.0f, e);
    scalars[0] = gw;
    scalars[1] = gb;
    scalars[2] = scale;
    scalars[3] = scale * gw;       // epilogue multiplier
    scalars[4] = 127.0f * scale;   // clip bound (exact)
    scalars[5] = ldexpf(1.0f, -e); // inv_scale (exact power of 2)
    sh_gb = gb;
  }
  __syncthreads();
  float gb = sh_gb;
  for (int i = t; i < 1024; i += 256) {
    float q = rintf(bias[i] / (gb + FEPS));
    q = fminf(fmaxf(q, -1.0f), 1.0f);
    bq[i] = q * gb;
  }
}

// ---------------- pass 3: fused quant + int8 MFMA GEMM ----------------------
// 512 blocks x 512 threads (8 waves), 64 KB LDS, launch_bounds(512,4) ->
// 2 blocks/CU co-resident (phase-A of one overlaps phase-B of the other).
// Phase A: quantize the block's 64x1024 fp32 x-panel into LDS (fragment-tiled
// int8), one __syncthreads.
// Phase B: NO barriers. Wave wv owns all 64 rows x cols np*256 + wv*32
// (unique per (np,wv) -> every wq tile read ONCE per block: 1 MB/block,
// 512 MB device, np/kt swept in the same order by all blocks so the active
// wq slice stays L2-hot). B global->VGPR depth-2 named-register prefetch;
// A via conflict-free ds_read_b128.
// Registers: acc[4][2]=32 AGPR + B prefetch 16 + A 16 + addr ~25 ≈ 90 arch
// -> fits the 128 unified cap with headroom (fixes r8's starvation).
__launch_bounds__(512, 4)
__global__ void k_megagemm(const float* __restrict__ x, const unsigned char* __restrict__ wq,
                           const float* __restrict__ scalars, const float* __restrict__ bq,
                           float* __restrict__ out) {
  __shared__ __align__(16) unsigned char Alds[65536];   // 64 tiles x 1KB

  const int tid = threadIdx.x;
  const int lane = tid & 63;
  const int wv = tid >> 6;          // 0..7
  const int mtile = blockIdx.x;     // 0..511 (64-row panel)
  const float qs = scalars[4], inv = scalars[5];

  // ---- Phase A: quantize 8 tiles per wave into LDS ----
  #pragma unroll
  for (int i = 0; i < 8; ++i) {
    const int tile = wv * 8 + i;    // 0..63 = mb*16 + kt
    const int mb = tile >> 4;       // 0..3
    const int kt = tile & 15;
    const float4* src = (const float4*)(x + (size_t)(mtile * 64 + mb * 16 + (lane >> 2)) * Kdim
                                          + kt * 64 + (lane & 3) * 16);
    unsigned o[4];
    #pragma unroll
    for (int v = 0; v < 4; ++v) {
      float4 f = src[v];
      int a = (int)rintf(fminf(fmaxf(f.x, -qs), qs) * inv);
      int b = (int)rintf(fminf(fmaxf(f.y, -qs), qs) * inv);
      int c = (int)rintf(fminf(fmaxf(f.z, -qs), qs) * inv);
      int d = (int)rintf(fminf(fmaxf(f.w, -qs), qs) * inv);
      o[v] = (unsigned)(a & 0xff) | ((unsigned)(b & 0xff) << 8) |
             ((unsigned)(c & 0xff) << 16) | ((unsigned)(d & 0xff) << 24);
    }
    uint4 pk; pk.x = o[0]; pk.y = o[1]; pk.z = o[2]; pk.w = o[3];
    const int lp = (lane >> 2) | ((lane & 3) << 4);   // fragment lane
    *(uint4*)(Alds + (size_t)tile * 1024 + lp * 16) = pk;
  }
  __syncthreads();   // the only barrier; Alds read-only below

  // ---- Phase B: 64 rows x 32 cols per wave per np, no barriers ----
  const float sg = scalars[3];
  const unsigned char* A0 = Alds + lane * 16;              // mb=0 tiles at kt*1024
  const unsigned char* A1 = Alds + 16 * 1024 + lane * 16;  // mb=1
  const unsigned char* A2 = Alds + 32 * 1024 + lane * 16;  // mb=2
  const unsigned char* A3 = Alds + 48 * 1024 + lane * 16;  // mb=3

#define MF8(a0_, a1_, a2_, a3_, B0, B1) do {                                       \
    acc[0][0] = __builtin_amdgcn_mfma_i32_16x16x64_i8(a0_, B0, acc[0][0], 0, 0, 0); \
    acc[0][1] = __builtin_amdgcn_mfma_i32_16x16x64_i8(a0_, B1, acc[0][1], 0, 0, 0); \
    acc[1][0] = __builtin_amdgcn_mfma_i32_16x16x64_i8(a1_, B0, acc[1][0], 0, 0, 0); \
    acc[1][1] = __builtin_amdgcn_mfma_i32_16x16x64_i8(a1_, B1, acc[1][1], 0, 0, 0); \
    acc[2][0] = __builtin_amdgcn_mfma_i32_16x16x64_i8(a2_, B0, acc[2][0], 0, 0, 0); \
    acc[2][1] = __builtin_amdgcn_mfma_i32_16x16x64_i8(a2_, B1, acc[2][1], 0, 0, 0); \
    acc[3][0] = __builtin_amdgcn_mfma_i32_16x16x64_i8(a3_, B0, acc[3][0], 0, 0, 0); \
    acc[3][1] = __builtin_amdgcn_mfma_i32_16x16x64_i8(a3_, B1, acc[3][1], 0, 0, 0); \
  } while (0)

  #pragma unroll 1
  for (int np = 0; np < 4; ++np) {
    int4v acc[4][2];
    #pragma unroll
    for (int i = 0; i < 4; ++i)
      #pragma unroll
      for (int j = 0; j < 2; ++j)
        acc[i][j] = (int4v){0, 0, 0, 0};

    // this wave's 2 N-blocks: nb = np*16 + wv*2 + {0,1}; tiles nb*16+kt
    const unsigned char* Bb = wq + ((size_t)(np * 16 + wv * 2) * 16) * 1024 + lane * 16;

    int4v pb0, pb1, qb0, qb1;
    pb0 = *(const int4v*)(Bb);
    pb1 = *(const int4v*)(Bb + 16 * 1024);
    qb0 = *(const int4v*)(Bb + 1024);
    qb1 = *(const int4v*)(Bb + 16 * 1024 + 1024);

    #pragma unroll
    for (int kt = 0; kt < 16; kt += 2) {
      int4v a0 = *(const int4v*)(A0 + (size_t)kt * 1024);
      int4v a1 = *(const int4v*)(A1 + (size_t)kt * 1024);
      int4v a2 = *(const int4v*)(A2 + (size_t)kt * 1024);
      int4v a3 = *(const int4v*)(A3 + (size_t)kt * 1024);
      __builtin_amdgcn_s_setprio(1);
      MF8(a0, a1, a2, a3, pb0, pb1);
      __builtin_amdgcn_s_setprio(0);
      if (kt + 2 < 16) {
        pb0 = *(const int4v*)(Bb + (size_t)(kt + 2) * 1024);
        pb1 = *(const int4v*)(Bb + 16 * 1024 + (size_t)(kt + 2) * 1024);
      }
      int4v a4 = *(const int4v*)(A0 + (size_t)(kt + 1) * 1024);
      int4v a5 = *(const int4v*)(A1 + (size_t)(kt + 1) * 1024);
      int4v a6 = *(const int4v*)(A2 + (size_t)(kt + 1) * 1024);
      int4v a7 = *(const int4v*)(A3 + (size_t)(kt + 1) * 1024);
      __builtin_amdgcn_s_setprio(1);
      MF8(a4, a5, a6, a7, qb0, qb1);
      __builtin_amdgcn_s_setprio(0);
      if (kt + 3 < 16) {
        qb0 = *(const int4v*)(Bb + (size_t)(kt + 3) * 1024);
        qb1 = *(const int4v*)(Bb + 16 * 1024 + (size_t)(kt + 3) * 1024);
      }
    }

    // epilogue for this 256-col group (stores overlap next np's loads)
    #pragma unroll
    for (int nj = 0; nj < 2; ++nj) {
      const int col = np * 256 + wv * 32 + nj * 16 + (lane & 15);
      const float bb = bq[col];
      #pragma unroll
      for (int mi = 0; mi < 4; ++mi) {
        const int rowb = mtile * 64 + mi * 16 + (lane >> 4) * 4;
        #pragma unroll
        for (int r = 0; r < 4; ++r)
          out[(size_t)(rowb + r) * Ndim + col] = (float)acc[mi][nj][r] * sg + bb;
      }
    }
  }
#undef MF8
}

extern "C" void kernel_launch(void* const* d_in, const int* in_sizes, int n_in,
                              void* d_out, int out_size, void* d_ws, size_t ws_size,
                              hipStream_t stream) {
  const float* x = (const float*)d_in[0];
  const float* weight = (const float*)d_in[1];
  const float* bias = (const float*)d_in[2];
  float* out = (float*)d_out;

  if (ws_size < WS_NEED) return;

  char* ws = (char*)d_ws;
  float* scalars = (float*)ws;
  float* partials = (float*)(ws + 1024);
  unsigned* pmax = (unsigned*)(ws + 4096);
  float* bq = (float*)(ws + 16384);
  unsigned char* wq = (unsigned char*)(ws + WQ_OFF);

  k_pre<<<2304, 256, 0, stream>>>((const uint4*)x, (const float4*)weight, pmax, partials);
  k_finalize2<<<256, 256, 0, stream>>>(bias, weight, partials, pmax, scalars, bq, wq);
  k_megagemm<<<512, 512, 0, stream>>>(x, wq, scalars, bq, out);
}

// Round 12
// 175.535 us; speedup vs baseline: 1.7277x; 1.7277x over previous
//
#include <hip/hip_runtime.h>

typedef __attribute__((ext_vector_type(4))) int int4v;

constexpr int Mdim = 32768;   // 8*4096
constexpr int Kdim = 1024;
constexpr int Ndim = 1024;
constexpr float FEPS = 1e-8f;

// ---------------- ws layout (bytes) ----------------
// 0      : float scalars[8]  {gamma_w, gamma_b, scale, sg, qs, inv_scale}
// 1024   : float partials[256]   (|W| partial sums)
// 4096   : unsigned pmax[2048]   (per-block |x| max bits)
// 16384  : float bq[1024]
// 32768  : int8 wq (1 MB)  -- TILED: tile t=(nb*16+kt) is 1KB; byte l*16 of tile t
//                             holds W[nb*16 + (l&15)][kt*64 + (l>>4)*16 .. +15]
constexpr size_t WQ_OFF = 32768;
constexpr size_t WS_NEED = WQ_OFF + (size_t)Ndim * Kdim;

// ---------------- pass 1 (merged): |x| absmax partials + |W| sum partials ----
__global__ void k_pre(const uint4* __restrict__ xv, const float4* __restrict__ wv,
                      unsigned* __restrict__ pmax, float* __restrict__ partials) {
  const int tid = threadIdx.x;
  if (blockIdx.x < 2048) {
    int i0 = blockIdx.x * 256 + tid;
    const int stride = 2048 * 256;
    const int n4 = Mdim * Kdim / 4;
    unsigned m = 0u;
    for (int i = i0; i < n4; i += stride) {
      uint4 v = xv[i];
      m = max(m, v.x & 0x7fffffffu);
      m = max(m, v.y & 0x7fffffffu);
      m = max(m, v.z & 0x7fffffffu);
      m = max(m, v.w & 0x7fffffffu);
    }
    #pragma unroll
    for (int off = 32; off > 0; off >>= 1)
      m = max(m, (unsigned)__shfl_down((int)m, off, 64));
    __shared__ unsigned red[4];
    if ((tid & 63) == 0) red[tid >> 6] = m;
    __syncthreads();
    if (tid == 0)
      pmax[blockIdx.x] = max(max(red[0], red[1]), max(red[2], red[3]));
  } else {
    int wb = blockIdx.x - 2048;
    float s = 0.f;
    const int stride = 256 * 256;
    const int n4 = Ndim * Kdim / 4;
    for (int i = wb * 256 + tid; i < n4; i += stride) {
      float4 v = wv[i];
      s += fabsf(v.x) + fabsf(v.y) + fabsf(v.z) + fabsf(v.w);
    }
    __shared__ float red[256];
    red[tid] = s;
    __syncthreads();
    for (int h = 128; h > 0; h >>= 1) {
      if (tid < h) red[tid] += red[tid + h];
      __syncthreads();
    }
    if (tid == 0) partials[wb] = red[0];
  }
}

// ---------------- pass 2: scalars + bias quant + W quant (256 blocks) --------
__global__ void k_finalize2(const float* __restrict__ bias, const float* __restrict__ w,
                            const float* __restrict__ partials, const unsigned* __restrict__ pmax,
                            float* __restrict__ scalars, float* __restrict__ bq,
                            unsigned char* __restrict__ wq) {
  __shared__ float red[256];
  const int t = threadIdx.x;
  const int b = blockIdx.x;

  red[t] = partials[t];
  __syncthreads();
  for (int h = 128; h > 0; h >>= 1) {
    if (t < h) red[t] += red[t + h];
    __syncthreads();
  }
  const float gw = red[0] / (1024.0f * 1024.0f);
  __syncthreads();
  const float inv_g = gw + FEPS;

  {
    const int tile = b * 4 + (t >> 6);   // 0..1023
    const int nb = tile >> 4;
    const int kt = tile & 15;
    const int l = t & 63;
    const float4* src = (const float4*)(w + (size_t)(nb * 16 + (l >> 2)) * Kdim + kt * 64 + (l & 3) * 16);
    unsigned o[4];
    #pragma unroll
    for (int v = 0; v < 4; ++v) {
      float4 f = src[v];
      int a  = (int)rintf(fminf(fmaxf(f.x / inv_g, -1.f), 1.f));
      int bb = (int)rintf(fminf(fmaxf(f.y / inv_g, -1.f), 1.f));
      int cc = (int)rintf(fminf(fmaxf(f.z / inv_g, -1.f), 1.f));
      int dd = (int)rintf(fminf(fmaxf(f.w / inv_g, -1.f), 1.f));
      o[v] = (unsigned)(a & 0xff) | ((unsigned)(bb & 0xff) << 8) |
             ((unsigned)(cc & 0xff) << 16) | ((unsigned)(dd & 0xff) << 24);
    }
    uint4 pk; pk.x = o[0]; pk.y = o[1]; pk.z = o[2]; pk.w = o[3];
    const int lp = (l >> 2) | ((l & 3) << 4);   // fragment lane
    *(uint4*)(wq + (size_t)tile * 1024 + lp * 16) = pk;
  }

  if (b != 0) return;

  __shared__ unsigned redu[256];
  __shared__ float sh_gb;
  unsigned m = 0u;
  #pragma unroll
  for (int i = 0; i < 8; ++i) m = max(m, pmax[t + 256 * i]);
  redu[t] = m;
  float s = fabsf(bias[t]) + fabsf(bias[t + 256]) + fabsf(bias[t + 512]) + fabsf(bias[t + 768]);
  red[t] = s;
  __syncthreads();
  for (int h = 128; h > 0; h >>= 1) {
    if (t < h) {
      red[t] += red[t + h];
      redu[t] = max(redu[t], redu[t + h]);
    }
    __syncthreads();
  }
  if (t == 0) {
    float gb = red[0] / 1024.0f;
    float maxval = __uint_as_float(redu[0]);
    float v = maxval / 127.0f + FEPS;
    int e = (int)((__float_as_uint(v) >> 23) & 0xff) - 127;
    float scale = ldexpf(1.0f, e);
    scalars[0] = gw;
    scalars[1] = gb;
    scalars[2] = scale;
    scalars[3] = scale * gw;       // epilogue multiplier
    scalars[4] = 127.0f * scale;   // clip bound (exact)
    scalars[5] = ldexpf(1.0f, -e); // inv_scale (exact power of 2)
    sh_gb = gb;
  }
  __syncthreads();
  float gb = sh_gb;
  for (int i = t; i < 1024; i += 256) {
    float q = rintf(bias[i] / (gb + FEPS));
    q = fminf(fmaxf(q, -1.0f), 1.0f);
    bq[i] = q * gb;
  }
}

// ---------------- pass 3: fused quant + int8 MFMA GEMM (r6 + K-chunk pipe) ---
// One block per mtile (128 rows), 16 waves, 128 KB LDS (1 block/CU).
// np=0 pass pipelines quantization into the K-loop (T14): K is processed in
// 4 chunks of 4 kt; while chunk c's 32 MFMAs run, each wave's x-loads for
// chunk c+1 are in flight; quant VALU + ds_write between MFMA bursts; one
// barrier per chunk. np=1..3 run on the fully-built Alds with no barriers
// (r6 behavior) + setprio around MFMA bursts (T5: 16 desynced waves).
// Quant-tile assignment: wave wv handles mb=wv>>1, kt = 4c + 2*(wv&1)+{0,1}.
__device__ __forceinline__ unsigned pack4q(float4 f, float qs, float inv) {
  int a = (int)rintf(fminf(fmaxf(f.x, -qs), qs) * inv);
  int b = (int)rintf(fminf(fmaxf(f.y, -qs), qs) * inv);
  int c = (int)rintf(fminf(fmaxf(f.z, -qs), qs) * inv);
  int d = (int)rintf(fminf(fmaxf(f.w, -qs), qs) * inv);
  return (unsigned)(a & 0xff) | ((unsigned)(b & 0xff) << 8) |
         ((unsigned)(c & 0xff) << 16) | ((unsigned)(d & 0xff) << 24);
}

__launch_bounds__(1024)
__global__ void k_megagemm(const float* __restrict__ x, const unsigned char* __restrict__ wq,
                           const float* __restrict__ scalars, const float* __restrict__ bq,
                           float* __restrict__ out) {
  __shared__ __align__(16) unsigned char Alds[131072];   // 128 tiles x 1KB

  const int tid = threadIdx.x;
  const int lane = tid & 63;
  const int wv = tid >> 6;          // 0..15
  const int mtile = blockIdx.x;     // 0..255
  const float qs = scalars[4], inv = scalars[5];
  const float sg = scalars[3];
  const int lp = (lane >> 2) | ((lane & 3) << 4);   // fragment lane for quant store

  // quant assignment
  const int qmb = wv >> 1;          // 0..7
  const int qk0 = (wv & 1) * 2;     // kt offset within chunk
  const float* qsrc = x + (size_t)(mtile * 128 + qmb * 16 + (lane >> 2)) * Kdim + (lane & 3) * 16;

  // compute wave mapping (r6): 4x4 grid, slice 32 rows x 64 cols per np
  const int wr = wv >> 2;           // 0..3
  const int wc = wv & 3;            // 0..3
  const unsigned char* A0 = Alds + (size_t)(wr * 2) * 16 * 1024 + lane * 16;
  const unsigned char* A1 = Alds + (size_t)(wr * 2 + 1) * 16 * 1024 + lane * 16;

#define QLOAD(r0, r1, r2, r3, ktt) do {                       \
    const float4* s_ = (const float4*)(qsrc + (ktt) * 64);    \
    r0 = s_[0]; r1 = s_[1]; r2 = s_[2]; r3 = s_[3];           \
  } while (0)

#define QSTORE(r0, r1, r2, r3, ktt) do {                                   \
    uint4 pk_;                                                             \
    pk_.x = pack4q(r0, qs, inv); pk_.y = pack4q(r1, qs, inv);              \
    pk_.z = pack4q(r2, qs, inv); pk_.w = pack4q(r3, qs, inv);              \
    *(uint4*)(Alds + (size_t)(qmb * 16 + (ktt)) * 1024 + lp * 16) = pk_;   \
  } while (0)

#define COMPUTE_KT(Bb_, ktt) do {                                                   \
    int4v b0 = *(const int4v*)((Bb_) + (size_t)(0 * 16 + (ktt)) * 1024);            \
    int4v b1 = *(const int4v*)((Bb_) + (size_t)(1 * 16 + (ktt)) * 1024);            \
    int4v b2 = *(const int4v*)((Bb_) + (size_t)(2 * 16 + (ktt)) * 1024);            \
    int4v b3 = *(const int4v*)((Bb_) + (size_t)(3 * 16 + (ktt)) * 1024);            \
    int4v a0 = *(const int4v*)(A0 + (size_t)(ktt) * 1024);                          \
    int4v a1 = *(const int4v*)(A1 + (size_t)(ktt) * 1024);                          \
    __builtin_amdgcn_s_setprio(1);                                                  \
    acc[0][0] = __builtin_amdgcn_mfma_i32_16x16x64_i8(a0, b0, acc[0][0], 0, 0, 0);  \
    acc[0][1] = __builtin_amdgcn_mfma_i32_16x16x64_i8(a0, b1, acc[0][1], 0, 0, 0);  \
    acc[0][2] = __builtin_amdgcn_mfma_i32_16x16x64_i8(a0, b2, acc[0][2], 0, 0, 0);  \
    acc[0][3] = __builtin_amdgcn_mfma_i32_16x16x64_i8(a0, b3, acc[0][3], 0, 0, 0);  \
    acc[1][0] = __builtin_amdgcn_mfma_i32_16x16x64_i8(a1, b0, acc[1][0], 0, 0, 0);  \
    acc[1][1] = __builtin_amdgcn_mfma_i32_16x16x64_i8(a1, b1, acc[1][1], 0, 0, 0);  \
    acc[1][2] = __builtin_amdgcn_mfma_i32_16x16x64_i8(a1, b2, acc[1][2], 0, 0, 0);  \
    acc[1][3] = __builtin_amdgcn_mfma_i32_16x16x64_i8(a1, b3, acc[1][3], 0, 0, 0);  \
    __builtin_amdgcn_s_setprio(0);                                                  \
  } while (0)

#define EPILOGUE(np_) do {                                                          \
    _Pragma("unroll")                                                               \
    for (int nj = 0; nj < 4; ++nj) {                                                \
      const int col = (np_) * 256 + wc * 64 + nj * 16 + (lane & 15);                \
      const float bb = bq[col];                                                     \
      _Pragma("unroll")                                                             \
      for (int mi = 0; mi < 2; ++mi) {                                              \
        const int rowb = mtile * 128 + wr * 64 + mi * 32 + (lane >> 4) * 4;         \
        _Pragma("unroll")                                                           \
        for (int r = 0; r < 4; ++r)                                                 \
          out[(size_t)(rowb + r) * Ndim + col] = (float)acc[mi][nj][r] * sg + bb;   \
      }                                                                             \
    }                                                                               \
  } while (0)

  // NOTE row mapping: acc[mi] covers A-tile (wr*2+mi) -> rows wr*32... careful:
  // A0 = tile mb=wr*2 (rows (wr*2)*16..), A1 = mb=wr*2+1. So mi stride is 16 rows
  // within the wave's 32-row slice: rowb = mtile*128 + (wr*2+mi)*16 + (lane>>4)*4.
#undef EPILOGUE
#define EPILOGUE(np_) do {                                                          \
    _Pragma("unroll")                                                               \
    for (int nj = 0; nj < 4; ++nj) {                                                \
      const int col = (np_) * 256 + wc * 64 + nj * 16 + (lane & 15);                \
      const float bb = bq[col];                                                     \
      _Pragma("unroll")                                                             \
      for (int mi = 0; mi < 2; ++mi) {                                              \
        const int rowb = mtile * 128 + (wr * 2 + mi) * 16 + (lane >> 4) * 4;        \
        _Pragma("unroll")                                                           \
        for (int r = 0; r < 4; ++r)                                                 \
          out[(size_t)(rowb + r) * Ndim + col] = (float)acc[mi][nj][r] * sg + bb;   \
      }                                                                             \
    }                                                                               \
  } while (0)

  // ---- prologue: quantize chunk 0 (kt 0..3), barrier ----
  {
    float4 r0, r1, r2, r3;
    QLOAD(r0, r1, r2, r3, qk0);
    QSTORE(r0, r1, r2, r3, qk0);
    QLOAD(r0, r1, r2, r3, qk0 + 1);
    QSTORE(r0, r1, r2, r3, qk0 + 1);
  }
  __syncthreads();

  // ---- np = 0: pipelined K-chunks ----
  {
    int4v acc[2][4];
    #pragma unroll
    for (int i = 0; i < 2; ++i)
      #pragma unroll
      for (int j = 0; j < 4; ++j)
        acc[i][j] = (int4v){0, 0, 0, 0};
    const unsigned char* Bb = wq + ((size_t)(0 * 16 + wc * 4) * 16) * 1024 + lane * 16;

    #pragma unroll
    for (int c = 0; c < 4; ++c) {
      float4 t0a, t0b, t0c, t0d;
      const int nk = 4 * (c + 1) + qk0;   // next chunk's first kt for this wave
      if (c < 3) QLOAD(t0a, t0b, t0c, t0d, nk);          // in flight under MFMAs
      COMPUTE_KT(Bb, 4 * c + 0);
      COMPUTE_KT(Bb, 4 * c + 1);
      float4 t1a, t1b, t1c, t1d;
      if (c < 3) {
        QSTORE(t0a, t0b, t0c, t0d, nk);
        QLOAD(t1a, t1b, t1c, t1d, nk + 1);               // in flight under MFMAs
      }
      COMPUTE_KT(Bb, 4 * c + 2);
      COMPUTE_KT(Bb, 4 * c + 3);
      if (c < 3) {
        QSTORE(t1a, t1b, t1c, t1d, nk + 1);
        __syncthreads();                                 // chunk c+1 ready
      }
    }
    EPILOGUE(0);
  }

  // ---- np = 1..3: pure compute on complete Alds (no barriers) ----
  #pragma unroll 1
  for (int np = 1; np < 4; ++np) {
    int4v acc[2][4];
    #pragma unroll
    for (int i = 0; i < 2; ++i)
      #pragma unroll
      for (int j = 0; j < 4; ++j)
        acc[i][j] = (int4v){0, 0, 0, 0};
    const unsigned char* Bb = wq + ((size_t)(np * 16 + wc * 4) * 16) * 1024 + lane * 16;
    #pragma unroll
    for (int kt = 0; kt < 16; ++kt)
      COMPUTE_KT(Bb, kt);
    EPILOGUE(np);
  }
#undef QLOAD
#undef QSTORE
#undef COMPUTE_KT
#undef EPILOGUE
}

extern "C" void kernel_launch(void* const* d_in, const int* in_sizes, int n_in,
                              void* d_out, int out_size, void* d_ws, size_t ws_size,
                              hipStream_t stream) {
  const float* x = (const float*)d_in[0];
  const float* weight = (const float*)d_in[1];
  const float* bias = (const float*)d_in[2];
  float* out = (float*)d_out;

  if (ws_size < WS_NEED) return;

  char* ws = (char*)d_ws;
  float* scalars = (float*)ws;
  float* partials = (float*)(ws + 1024);
  unsigned* pmax = (unsigned*)(ws + 4096);
  float* bq = (float*)(ws + 16384);
  unsigned char* wq = (unsigned char*)(ws + WQ_OFF);

  k_pre<<<2304, 256, 0, stream>>>((const uint4*)x, (const float4*)weight, pmax, partials);
  k_finalize2<<<256, 256, 0, stream>>>(bias, weight, partials, pmax, scalars, bq, wq);
  k_megagemm<<<256, 1024, 0, stream>>>(x, wq, scalars, bq, out);
}

// Round 13
// 100.223 us; speedup vs baseline: 3.0260x; 1.7514x over previous
//
#include <hip/hip_runtime.h>

typedef __attribute__((ext_vector_type(4))) int int4v;

constexpr int Mdim = 32768;   // 8*4096
constexpr int Kdim = 1024;
constexpr int Ndim = 1024;
constexpr float FEPS = 1e-8f;

// ---------------- ws layout (bytes) ----------------
// 0      : float scalars[8]  {gamma_w, gamma_b, scale, sg, qs, inv_scale}
// 1024   : float partials[256]   (|W| partial sums)
// 4096   : unsigned pmax[2048]   (per-block |x| max bits)
// 16384  : float bq[1024]
// 32768  : int8 wq (1 MB)  -- TILED: tile t=(nb*16+kt) is 1KB; byte l*16 of tile t
//                             holds W[nb*16 + (l&15)][kt*64 + (l>>4)*16 .. +15]
constexpr size_t WQ_OFF = 32768;
constexpr size_t WS_NEED = WQ_OFF + (size_t)Ndim * Kdim;

// ---------------- pass 1 (merged): |x| absmax partials + |W| sum partials ----
__global__ void k_pre(const uint4* __restrict__ xv, const float4* __restrict__ wv,
                      unsigned* __restrict__ pmax, float* __restrict__ partials) {
  const int tid = threadIdx.x;
  if (blockIdx.x < 2048) {
    int i0 = blockIdx.x * 256 + tid;
    const int stride = 2048 * 256;
    const int n4 = Mdim * Kdim / 4;
    unsigned m = 0u;
    for (int i = i0; i < n4; i += stride) {
      uint4 v = xv[i];
      m = max(m, v.x & 0x7fffffffu);
      m = max(m, v.y & 0x7fffffffu);
      m = max(m, v.z & 0x7fffffffu);
      m = max(m, v.w & 0x7fffffffu);
    }
    #pragma unroll
    for (int off = 32; off > 0; off >>= 1)
      m = max(m, (unsigned)__shfl_down((int)m, off, 64));
    __shared__ unsigned red[4];
    if ((tid & 63) == 0) red[tid >> 6] = m;
    __syncthreads();
    if (tid == 0)
      pmax[blockIdx.x] = max(max(red[0], red[1]), max(red[2], red[3]));
  } else {
    int wb = blockIdx.x - 2048;
    float s = 0.f;
    const int stride = 256 * 256;
    const int n4 = Ndim * Kdim / 4;
    for (int i = wb * 256 + tid; i < n4; i += stride) {
      float4 v = wv[i];
      s += fabsf(v.x) + fabsf(v.y) + fabsf(v.z) + fabsf(v.w);
    }
    __shared__ float red[256];
    red[tid] = s;
    __syncthreads();
    for (int h = 128; h > 0; h >>= 1) {
      if (tid < h) red[tid] += red[tid + h];
      __syncthreads();
    }
    if (tid == 0) partials[wb] = red[0];
  }
}

// ---------------- pass 2: scalars + bias quant + W quant (256 blocks) --------
__global__ void k_finalize2(const float* __restrict__ bias, const float* __restrict__ w,
                            const float* __restrict__ partials, const unsigned* __restrict__ pmax,
                            float* __restrict__ scalars, float* __restrict__ bq,
                            unsigned char* __restrict__ wq) {
  __shared__ float red[256];
  const int t = threadIdx.x;
  const int b = blockIdx.x;

  red[t] = partials[t];
  __syncthreads();
  for (int h = 128; h > 0; h >>= 1) {
    if (t < h) red[t] += red[t + h];
    __syncthreads();
  }
  const float gw = red[0] / (1024.0f * 1024.0f);
  __syncthreads();
  const float inv_g = gw + FEPS;

  {
    const int tile = b * 4 + (t >> 6);   // 0..1023
    const int nb = tile >> 4;
    const int kt = tile & 15;
    const int l = t & 63;
    const float4* src = (const float4*)(w + (size_t)(nb * 16 + (l >> 2)) * Kdim + kt * 64 + (l & 3) * 16);
    unsigned o[4];
    #pragma unroll
    for (int v = 0; v < 4; ++v) {
      float4 f = src[v];
      int a  = (int)rintf(fminf(fmaxf(f.x / inv_g, -1.f), 1.f));
      int bb = (int)rintf(fminf(fmaxf(f.y / inv_g, -1.f), 1.f));
      int cc = (int)rintf(fminf(fmaxf(f.z / inv_g, -1.f), 1.f));
      int dd = (int)rintf(fminf(fmaxf(f.w / inv_g, -1.f), 1.f));
      o[v] = (unsigned)(a & 0xff) | ((unsigned)(bb & 0xff) << 8) |
             ((unsigned)(cc & 0xff) << 16) | ((unsigned)(dd & 0xff) << 24);
    }
    uint4 pk; pk.x = o[0]; pk.y = o[1]; pk.z = o[2]; pk.w = o[3];
    const int lp = (l >> 2) | ((l & 3) << 4);   // fragment lane
    *(uint4*)(wq + (size_t)tile * 1024 + lp * 16) = pk;
  }

  if (b != 0) return;

  __shared__ unsigned redu[256];
  __shared__ float sh_gb;
  unsigned m = 0u;
  #pragma unroll
  for (int i = 0; i < 8; ++i) m = max(m, pmax[t + 256 * i]);
  redu[t] = m;
  float s = fabsf(bias[t]) + fabsf(bias[t + 256]) + fabsf(bias[t + 512]) + fabsf(bias[t + 768]);
  red[t] = s;
  __syncthreads();
  for (int h = 128; h > 0; h >>= 1) {
    if (t < h) {
      red[t] += red[t + h];
      redu[t] = max(redu[t], redu[t + h]);
    }
    __syncthreads();
  }
  if (t == 0) {
    float gb = red[0] / 1024.0f;
    float maxval = __uint_as_float(redu[0]);
    float v = maxval / 127.0f + FEPS;
    int e = (int)((__float_as_uint(v) >> 23) & 0xff) - 127;
    float scale = ldexpf(1.0f, e);
    scalars[0] = gw;
    scalars[1] = gb;
    scalars[2] = scale;
    scalars[3] = scale * gw;       // epilogue multiplier
    scalars[4] = 127.0f * scale;   // clip bound (exact)
    scalars[5] = ldexpf(1.0f, -e); // inv_scale (exact power of 2)
    sh_gb = gb;
  }
  __syncthreads();
  float gb = sh_gb;
  for (int i = t; i < 1024; i += 256) {
    float q = rintf(bias[i] / (gb + FEPS));
    q = fminf(fmaxf(q, -1.0f), 1.0f);
    bq[i] = q * gb;
  }
}

// ---------------- pass 3: fused quant + int8 MFMA GEMM (r6 structure) -------
// One block per mtile (128 rows), 16 waves, 128 KB LDS. Phase A: quantize the
// 128x1024 fp32 x-panel into LDS (fragment-tiled int8), one barrier.
// Phase B: barrier-free; A-frags from LDS, B-frags global->VGPR from the
// L2/L1-resident tiled wq. Wave (wr=wv>>2, wc=wv&3) owns rows wr*32, cols
// wc*64 per 256-col group; np=0..3. Per (np,kt) the block's B working set is
// 16 KB -> L1-shared across the 4 row-wave-groups.
// r13 deltas vs r6 (both local): s_setprio(1) around MFMA bursts (T5 -- the
// 16 desynced waves are the regime where it measured +4-7%); non-temporal
// epilogue stores (keep the 128 MB out stream from evicting x/wq in L2/L3).
__launch_bounds__(1024)
__global__ void k_megagemm(const float* __restrict__ x, const unsigned char* __restrict__ wq,
                           const float* __restrict__ scalars, const float* __restrict__ bq,
                           float* __restrict__ out) {
  __shared__ __align__(16) unsigned char Alds[131072];   // 128 tiles x 1KB

  const int tid = threadIdx.x;
  const int lane = tid & 63;
  const int wv = tid >> 6;          // 0..15
  const int mtile = blockIdx.x;     // 0..255
  const float qs = scalars[4], inv = scalars[5];

  // ---- Phase A: quantize 8 tiles per wave into LDS ----
  #pragma unroll
  for (int i = 0; i < 8; ++i) {
    const int tile = wv * 8 + i;    // 0..127
    const int mb = tile >> 4;
    const int kt = tile & 15;
    const float4* src = (const float4*)(x + (size_t)(mtile * 128 + mb * 16 + (lane >> 2)) * Kdim
                                          + kt * 64 + (lane & 3) * 16);
    unsigned o[4];
    #pragma unroll
    for (int v = 0; v < 4; ++v) {
      float4 f = src[v];
      int a = (int)rintf(fminf(fmaxf(f.x, -qs), qs) * inv);
      int b = (int)rintf(fminf(fmaxf(f.y, -qs), qs) * inv);
      int c = (int)rintf(fminf(fmaxf(f.z, -qs), qs) * inv);
      int d = (int)rintf(fminf(fmaxf(f.w, -qs), qs) * inv);
      o[v] = (unsigned)(a & 0xff) | ((unsigned)(b & 0xff) << 8) |
             ((unsigned)(c & 0xff) << 16) | ((unsigned)(d & 0xff) << 24);
    }
    uint4 pk; pk.x = o[0]; pk.y = o[1]; pk.z = o[2]; pk.w = o[3];
    const int lp = (lane >> 2) | ((lane & 3) << 4);   // fragment lane
    *(uint4*)(Alds + (size_t)tile * 1024 + lp * 16) = pk;
  }
  __syncthreads();   // the only barrier; Alds is read-only below

  // ---- Phase B: GEMM ----
  const int wr = wv >> 2;           // 0..3 : rows wr*32
  const int wc = wv & 3;            // 0..3 : cols wc*64 (within 256-wide group)
  const float sg = scalars[3];
  const unsigned char* Alds_a0 = Alds + (size_t)(wr * 2) * 16 * 1024 + lane * 16;
  const unsigned char* Alds_a1 = Alds + (size_t)(wr * 2 + 1) * 16 * 1024 + lane * 16;

  for (int np = 0; np < 4; ++np) {
    int4v acc[2][4];
    #pragma unroll
    for (int i = 0; i < 2; ++i)
      #pragma unroll
      for (int j = 0; j < 4; ++j)
        acc[i][j] = (int4v){0, 0, 0, 0};

    const unsigned char* Bb = wq + ((size_t)(np * 16 + wc * 4) * 16) * 1024 + lane * 16;

    #pragma unroll
    for (int kt = 0; kt < 16; ++kt) {
      int4v b0 = *(const int4v*)(Bb + (size_t)(0 * 16 + kt) * 1024);
      int4v b1 = *(const int4v*)(Bb + (size_t)(1 * 16 + kt) * 1024);
      int4v b2 = *(const int4v*)(Bb + (size_t)(2 * 16 + kt) * 1024);
      int4v b3 = *(const int4v*)(Bb + (size_t)(3 * 16 + kt) * 1024);
      int4v a0 = *(const int4v*)(Alds_a0 + (size_t)kt * 1024);
      int4v a1 = *(const int4v*)(Alds_a1 + (size_t)kt * 1024);
      __builtin_amdgcn_s_setprio(1);
      acc[0][0] = __builtin_amdgcn_mfma_i32_16x16x64_i8(a0, b0, acc[0][0], 0, 0, 0);
      acc[0][1] = __builtin_amdgcn_mfma_i32_16x16x64_i8(a0, b1, acc[0][1], 0, 0, 0);
      acc[0][2] = __builtin_amdgcn_mfma_i32_16x16x64_i8(a0, b2, acc[0][2], 0, 0, 0);
      acc[0][3] = __builtin_amdgcn_mfma_i32_16x16x64_i8(a0, b3, acc[0][3], 0, 0, 0);
      acc[1][0] = __builtin_amdgcn_mfma_i32_16x16x64_i8(a1, b0, acc[1][0], 0, 0, 0);
      acc[1][1] = __builtin_amdgcn_mfma_i32_16x16x64_i8(a1, b1, acc[1][1], 0, 0, 0);
      acc[1][2] = __builtin_amdgcn_mfma_i32_16x16x64_i8(a1, b2, acc[1][2], 0, 0, 0);
      acc[1][3] = __builtin_amdgcn_mfma_i32_16x16x64_i8(a1, b3, acc[1][3], 0, 0, 0);
      __builtin_amdgcn_s_setprio(0);
    }

    // epilogue for this 256-col group; non-temporal stores keep the output
    // stream from evicting x/wq from L2/L3.
    #pragma unroll
    for (int ni = 0; ni < 4; ++ni) {
      const int col = np * 256 + wc * 64 + ni * 16 + (lane & 15);
      const float bb = bq[col];
      #pragma unroll
      for (int mi = 0; mi < 2; ++mi) {
        const int rowb = mtile * 128 + (wr * 2 + mi) * 16 + (lane >> 4) * 4;
        #pragma unroll
        for (int r = 0; r < 4; ++r)
          __builtin_nontemporal_store((float)acc[mi][ni][r] * sg + bb,
                                      &out[(size_t)(rowb + r) * Ndim + col]);
      }
    }
  }
}

extern "C" void kernel_launch(void* const* d_in, const int* in_sizes, int n_in,
                              void* d_out, int out_size, void* d_ws, size_t ws_size,
                              hipStream_t stream) {
  const float* x = (const float*)d_in[0];
  const float* weight = (const float*)d_in[1];
  const float* bias = (const float*)d_in[2];
  float* out = (float*)d_out;

  if (ws_size < WS_NEED) return;

  char* ws = (char*)d_ws;
  float* scalars = (float*)ws;
  float* partials = (float*)(ws + 1024);
  unsigned* pmax = (unsigned*)(ws + 4096);
  float* bq = (float*)(ws + 16384);
  unsigned char* wq = (unsigned char*)(ws + WQ_OFF);

  k_pre<<<2304, 256, 0, stream>>>((const uint4*)x, (const float4*)weight, pmax, partials);
  k_finalize2<<<256, 256, 0, stream>>>(bias, weight, partials, pmax, scalars, bq, wq);
  k_megagemm<<<256, 1024, 0, stream>>>(x, wq, scalars, bq, out);
}

// Round 14
// 96.154 us; speedup vs baseline: 3.1540x; 1.0423x over previous
//
#include <hip/hip_runtime.h>

typedef __attribute__((ext_vector_type(4))) int int4v;

constexpr int Mdim = 32768;   // 8*4096
constexpr int Kdim = 1024;
constexpr int Ndim = 1024;
constexpr float FEPS = 1e-8f;

// ---------------- ws layout (bytes) ----------------
// 0      : float scalars[8]  {gamma_w, gamma_b, scale, sg, qs, inv_scale}
// 1024   : float partials[256]   (|W| partial sums)
// 4096   : unsigned pmax[2048]   (per-block |x| max bits)
// 16384  : float bq[1024]
// 32768  : int8 wq (1 MB)  -- TILED: tile t=(nb*16+kt) is 1KB; byte l*16 of tile t
//                             holds W[nb*16 + (l&15)][kt*64 + (l>>4)*16 .. +15]
constexpr size_t WQ_OFF = 32768;
constexpr size_t WS_NEED = WQ_OFF + (size_t)Ndim * Kdim;

// ---------------- pass 1 (merged): |x| absmax partials + |W| sum partials ----
// blocks [0,2048): absmax of x -> pmax[b]; blocks [2048,2304): |W| sums -> partials[b-2048]
__global__ void k_pre(const uint4* __restrict__ xv, const float4* __restrict__ wv,
                      unsigned* __restrict__ pmax, float* __restrict__ partials) {
  const int tid = threadIdx.x;
  if (blockIdx.x < 2048) {
    int i0 = blockIdx.x * 256 + tid;
    const int stride = 2048 * 256;
    const int n4 = Mdim * Kdim / 4;
    unsigned m = 0u;
    for (int i = i0; i < n4; i += stride) {
      uint4 v = xv[i];
      m = max(m, v.x & 0x7fffffffu);
      m = max(m, v.y & 0x7fffffffu);
      m = max(m, v.z & 0x7fffffffu);
      m = max(m, v.w & 0x7fffffffu);
    }
    #pragma unroll
    for (int off = 32; off > 0; off >>= 1)
      m = max(m, (unsigned)__shfl_down((int)m, off, 64));
    __shared__ unsigned red[4];
    if ((tid & 63) == 0) red[tid >> 6] = m;
    __syncthreads();
    if (tid == 0)
      pmax[blockIdx.x] = max(max(red[0], red[1]), max(red[2], red[3]));
  } else {
    int wb = blockIdx.x - 2048;
    float s = 0.f;
    const int stride = 256 * 256;
    const int n4 = Ndim * Kdim / 4;
    for (int i = wb * 256 + tid; i < n4; i += stride) {
      float4 v = wv[i];
      s += fabsf(v.x) + fabsf(v.y) + fabsf(v.z) + fabsf(v.w);
    }
    __shared__ float red[256];
    red[tid] = s;
    __syncthreads();
    for (int h = 128; h > 0; h >>= 1) {
      if (tid < h) red[tid] += red[tid + h];
      __syncthreads();
    }
    if (tid == 0) partials[wb] = red[0];
  }
}

// ---------------- pass 2: scalars + bias quant + W quant (256 blocks) --------
// Every block reduces partials[256] locally -> gamma_w, then ternary-quantizes
// its 4 W-tiles into the tiled wq layout. Block 0 additionally computes
// scalars[] and bq[] (identical math to prior rounds).
__global__ void k_finalize2(const float* __restrict__ bias, const float* __restrict__ w,
                            const float* __restrict__ partials, const unsigned* __restrict__ pmax,
                            float* __restrict__ scalars, float* __restrict__ bq,
                            unsigned char* __restrict__ wq) {
  __shared__ float red[256];
  const int t = threadIdx.x;
  const int b = blockIdx.x;

  // local gamma_w from the 256 fixed partials
  red[t] = partials[t];
  __syncthreads();
  for (int h = 128; h > 0; h >>= 1) {
    if (t < h) red[t] += red[t + h];
    __syncthreads();
  }
  const float gw = red[0] / (1024.0f * 1024.0f);
  __syncthreads();
  const float inv_g = gw + FEPS;

  // quantize 4 W tiles: tile = b*4 + (t>>6); coalesced read, permuted write
  {
    const int tile = b * 4 + (t >> 6);   // 0..1023
    const int nb = tile >> 4;
    const int kt = tile & 15;
    const int l = t & 63;
    const float4* src = (const float4*)(w + (size_t)(nb * 16 + (l >> 2)) * Kdim + kt * 64 + (l & 3) * 16);
    unsigned o[4];
    #pragma unroll
    for (int v = 0; v < 4; ++v) {
      float4 f = src[v];
      int a  = (int)rintf(fminf(fmaxf(f.x / inv_g, -1.f), 1.f));
      int bb = (int)rintf(fminf(fmaxf(f.y / inv_g, -1.f), 1.f));
      int cc = (int)rintf(fminf(fmaxf(f.z / inv_g, -1.f), 1.f));
      int dd = (int)rintf(fminf(fmaxf(f.w / inv_g, -1.f), 1.f));
      o[v] = (unsigned)(a & 0xff) | ((unsigned)(bb & 0xff) << 8) |
             ((unsigned)(cc & 0xff) << 16) | ((unsigned)(dd & 0xff) << 24);
    }
    uint4 pk; pk.x = o[0]; pk.y = o[1]; pk.z = o[2]; pk.w = o[3];
    const int lp = (l >> 2) | ((l & 3) << 4);   // fragment lane
    *(uint4*)(wq + (size_t)tile * 1024 + lp * 16) = pk;
  }

  if (b != 0) return;

  // block 0: absmax reduce + scalars + bq
  __shared__ unsigned redu[256];
  __shared__ float sh_gb;
  unsigned m = 0u;
  #pragma unroll
  for (int i = 0; i < 8; ++i) m = max(m, pmax[t + 256 * i]);
  redu[t] = m;
  float s = fabsf(bias[t]) + fabsf(bias[t + 256]) + fabsf(bias[t + 512]) + fabsf(bias[t + 768]);
  red[t] = s;
  __syncthreads();
  for (int h = 128; h > 0; h >>= 1) {
    if (t < h) {
      red[t] += red[t + h];
      redu[t] = max(redu[t], redu[t + h]);
    }
    __syncthreads();
  }
  if (t == 0) {
    float gb = red[0] / 1024.0f;
    float maxval = __uint_as_float(redu[0]);
    float v = maxval / 127.0f + FEPS;
    int e = (int)((__float_as_uint(v) >> 23) & 0xff) - 127;
    float scale = ldexpf(1.0f, e);
    scalars[0] = gw;
    scalars[1] = gb;
    scalars[2] = scale;
    scalars[3] = scale * gw;       // epilogue multiplier
    scalars[4] = 127.0f * scale;   // clip bound (exact)
    scalars[5] = ldexpf(1.0f, -e); // inv_scale (exact power of 2)
    sh_gb = gb;
  }
  __syncthreads();
  float gb = sh_gb;
  for (int i = t; i < 1024; i += 256) {
    float q = rintf(bias[i] / (gb + FEPS));
    q = fminf(fmaxf(q, -1.0f), 1.0f);
    bq[i] = q * gb;
  }
}

// ---------------- pass 3: fused quant + int8 MFMA GEMM (r6, measured best) --
// One block per mtile (128 rows), 16 waves. Phase A: quantize this block's
// 128x1024 fp32 x-panel into LDS (fragment-tiled int8, 128 KB), one barrier.
// Phase B: barrier-free K-loop; A-frags from LDS (linear ds_read_b128,
// conflict-free), B-frags direct global->VGPR from L2-resident tiled wq.
// Wave (wr=wv>>2, wc=wv&3) owns rows (wr*2,wr*2+1)*16, cols wc*64 within each
// 256-col group; np=0..3 covers the 1024 output cols. Per (np,kt) the block's
// B working set is 16 KB -> L1-shared across the 4 row-wave-groups.
// NOTE (r13 lesson): s_setprio around the MFMAs and nontemporal epilogue
// stores BOTH regressed this kernel (+10 us combined) -- keep plain.
__launch_bounds__(1024)
__global__ void k_megagemm(const float* __restrict__ x, const unsigned char* __restrict__ wq,
                           const float* __restrict__ scalars, const float* __restrict__ bq,
                           float* __restrict__ out) {
  __shared__ __align__(16) unsigned char Alds[131072];   // 128 tiles x 1KB

  const int tid = threadIdx.x;
  const int lane = tid & 63;
  const int wv = tid >> 6;          // 0..15
  const int mtile = blockIdx.x;     // 0..255
  const float qs = scalars[4], inv = scalars[5];

  // ---- Phase A: quantize 8 tiles per wave into LDS ----
  #pragma unroll
  for (int i = 0; i < 8; ++i) {
    const int tile = wv * 8 + i;    // 0..127
    const int mb = tile >> 4;
    const int kt = tile & 15;
    const float4* src = (const float4*)(x + (size_t)(mtile * 128 + mb * 16 + (lane >> 2)) * Kdim
                                          + kt * 64 + (lane & 3) * 16);
    unsigned o[4];
    #pragma unroll
    for (int v = 0; v < 4; ++v) {
      float4 f = src[v];
      int a = (int)rintf(fminf(fmaxf(f.x, -qs), qs) * inv);
      int b = (int)rintf(fminf(fmaxf(f.y, -qs), qs) * inv);
      int c = (int)rintf(fminf(fmaxf(f.z, -qs), qs) * inv);
      int d = (int)rintf(fminf(fmaxf(f.w, -qs), qs) * inv);
      o[v] = (unsigned)(a & 0xff) | ((unsigned)(b & 0xff) << 8) |
             ((unsigned)(c & 0xff) << 16) | ((unsigned)(d & 0xff) << 24);
    }
    uint4 pk; pk.x = o[0]; pk.y = o[1]; pk.z = o[2]; pk.w = o[3];
    const int lp = (lane >> 2) | ((lane & 3) << 4);   // fragment lane
    *(uint4*)(Alds + (size_t)tile * 1024 + lp * 16) = pk;
  }
  __syncthreads();   // the only barrier; Alds is read-only below

  // ---- Phase B: GEMM ----
  const int wr = wv >> 2;           // 0..3
  const int wc = wv & 3;            // 0..3 : cols wc*64 (within 256-wide group)
  const float sg = scalars[3];
  const unsigned char* Alds_a0 = Alds + (size_t)(wr * 2) * 16 * 1024 + lane * 16;
  const unsigned char* Alds_a1 = Alds + (size_t)(wr * 2 + 1) * 16 * 1024 + lane * 16;

  for (int np = 0; np < 4; ++np) {
    int4v acc[2][4];
    #pragma unroll
    for (int i = 0; i < 2; ++i)
      #pragma unroll
      for (int j = 0; j < 4; ++j)
        acc[i][j] = (int4v){0, 0, 0, 0};

    const unsigned char* Bb = wq + ((size_t)(np * 16 + wc * 4) * 16) * 1024 + lane * 16;

    #pragma unroll
    for (int kt = 0; kt < 16; ++kt) {
      int4v b0 = *(const int4v*)(Bb + (size_t)(0 * 16 + kt) * 1024);
      int4v b1 = *(const int4v*)(Bb + (size_t)(1 * 16 + kt) * 1024);
      int4v b2 = *(const int4v*)(Bb + (size_t)(2 * 16 + kt) * 1024);
      int4v b3 = *(const int4v*)(Bb + (size_t)(3 * 16 + kt) * 1024);
      int4v a0 = *(const int4v*)(Alds_a0 + (size_t)kt * 1024);
      int4v a1 = *(const int4v*)(Alds_a1 + (size_t)kt * 1024);
      acc[0][0] = __builtin_amdgcn_mfma_i32_16x16x64_i8(a0, b0, acc[0][0], 0, 0, 0);
      acc[0][1] = __builtin_amdgcn_mfma_i32_16x16x64_i8(a0, b1, acc[0][1], 0, 0, 0);
      acc[0][2] = __builtin_amdgcn_mfma_i32_16x16x64_i8(a0, b2, acc[0][2], 0, 0, 0);
      acc[0][3] = __builtin_amdgcn_mfma_i32_16x16x64_i8(a0, b3, acc[0][3], 0, 0, 0);
      acc[1][0] = __builtin_amdgcn_mfma_i32_16x16x64_i8(a1, b0, acc[1][0], 0, 0, 0);
      acc[1][1] = __builtin_amdgcn_mfma_i32_16x16x64_i8(a1, b1, acc[1][1], 0, 0, 0);
      acc[1][2] = __builtin_amdgcn_mfma_i32_16x16x64_i8(a1, b2, acc[1][2], 0, 0, 0);
      acc[1][3] = __builtin_amdgcn_mfma_i32_16x16x64_i8(a1, b3, acc[1][3], 0, 0, 0);
    }

    // epilogue for this 256-col group (writes overlap next group's compute)
    #pragma unroll
    for (int ni = 0; ni < 4; ++ni) {
      const int col = np * 256 + wc * 64 + ni * 16 + (lane & 15);
      const float bb = bq[col];
      #pragma unroll
      for (int mi = 0; mi < 2; ++mi) {
        const int rowb = mtile * 128 + (wr * 2 + mi) * 16 + (lane >> 4) * 4;
        #pragma unroll
        for (int r = 0; r < 4; ++r)
          out[(size_t)(rowb + r) * Ndim + col] = (float)acc[mi][ni][r] * sg + bb;
      }
    }
  }
}

extern "C" void kernel_launch(void* const* d_in, const int* in_sizes, int n_in,
                              void* d_out, int out_size, void* d_ws, size_t ws_size,
                              hipStream_t stream) {
  const float* x = (const float*)d_in[0];
  const float* weight = (const float*)d_in[1];
  const float* bias = (const float*)d_in[2];
  float* out = (float*)d_out;

  if (ws_size < WS_NEED) return;

  char* ws = (char*)d_ws;
  float* scalars = (float*)ws;
  float* partials = (float*)(ws + 1024);
  unsigned* pmax = (unsigned*)(ws + 4096);
  float* bq = (float*)(ws + 16384);
  unsigned char* wq = (unsigned char*)(ws + WQ_OFF);

  k_pre<<<2304, 256, 0, stream>>>((const uint4*)x, (const float4*)weight, pmax, partials);
  k_finalize2<<<256, 256, 0, stream>>>(bias, weight, partials, pmax, scalars, bq, wq);
  k_megagemm<<<256, 1024, 0, stream>>>(x, wq, scalars, bq, out);
}